// Round 2
// baseline (223.975 us; speedup 1.0000x reference)
//
#include <hip/hip_runtime.h>
#include <hip/hip_bf16.h>

typedef __bf16 bf16x8_t __attribute__((ext_vector_type(8)));
typedef float f32x4_t __attribute__((ext_vector_type(4)));

#define MFMA_BF16(a, b, c) __builtin_amdgcn_mfma_f32_16x16x32_bf16((a), (b), (c), 0, 0, 0)
#define BARRIER() __builtin_amdgcn_s_barrier()
#define WAIT_LGKM0() asm volatile("s_waitcnt lgkmcnt(0)" ::: "memory")

static constexpr int T_DIM = 512;
static constexpr int H_DIM = 7168;
static constexpr int F_DIM = 2048;

__device__ __forceinline__ ushort f2bf(float f) {
    return __builtin_bit_cast(ushort, __float2bfloat16(f));
}

// XOR-swizzle for [rows][64-ushort] LDS tiles, 16B-unit granularity.
__device__ __forceinline__ int swzu(int row, int c16) {
    return (row << 6) + (((c16) ^ (row & 7)) << 3);
}
// 8B-granular variant for staging writes (c8 in [0,16))
__device__ __forceinline__ int swz8(int row, int c8) {
    return (row << 6) + ((((c8 >> 1) ^ (row & 7))) << 3) + ((c8 & 1) << 2);
}

__global__ void cvt_x_kernel(const float* __restrict__ in, ushort* __restrict__ outp, int n4) {
    int i = blockIdx.x * 256 + threadIdx.x;
    if (i < n4) {
        float4 v = reinterpret_cast<const float4*>(in)[i];
        ushort4 o;
        o.x = f2bf(v.x); o.y = f2bf(v.y); o.z = f2bf(v.z); o.w = f2bf(v.w);
        reinterpret_cast<ushort4*>(outp)[i] = o;
    }
}

// ---------------- gate+up fused GEMM ----------------
// BM=64, BN=64, BK=64. 2-deep register prefetch + double-buffered LDS +
// raw barriers (no compiler vmcnt(0) drain). One barrier per k-tile.
__global__ __launch_bounds__(256, 1) void gate_up_kernel(
    const ushort* __restrict__ xb, const float* __restrict__ wg,
    const float* __restrict__ sg, const float* __restrict__ wu,
    const float* __restrict__ su, ushort* __restrict__ hb)
{
    __shared__ ushort As[2][64 * 64];
    __shared__ ushort Bg[2][64 * 64];
    __shared__ ushort Bu[2][64 * 64];

    const int tid = threadIdx.x;
    const int lane = tid & 63;
    const int wid = tid >> 6;
    const int wr = wid >> 1, wc = wid & 1;
    const int bn = blockIdx.x, bm = blockIdx.y;
    const int m0 = bm * 64, n0 = bn * 64;

    const int xr = tid >> 3, xc = tid & 7;
    const int wrow = tid >> 4, wc4 = tid & 15;
    const int NT = H_DIM / 64;  // 112 (even)

    uint4 rx[2][2];
    float4 rg[2][4], ru[2][4];
    f32x4_t accg[2][2] = {};
    f32x4_t accu[2][2] = {};

    auto LOADG = [&](int kt, int s) {
        const int k0 = kt * 64;
        #pragma unroll
        for (int p = 0; p < 2; ++p)
            rx[s][p] = *reinterpret_cast<const uint4*>(
                &xb[(size_t)(m0 + p * 32 + xr) * H_DIM + k0 + xc * 8]);
        #pragma unroll
        for (int p = 0; p < 4; ++p) {
            const size_t off = (size_t)(n0 + p * 16 + wrow) * H_DIM + k0 + wc4 * 4;
            rg[s][p] = *reinterpret_cast<const float4*>(&wg[off]);
            ru[s][p] = *reinterpret_cast<const float4*>(&wu[off]);
        }
    };

    auto STORE = [&](int kt, int s, int b) {
        const float s_g = sg[(bn >> 1) * (H_DIM / 128) + (kt >> 1)];
        const float s_u = su[(bn >> 1) * (H_DIM / 128) + (kt >> 1)];
        #pragma unroll
        for (int p = 0; p < 2; ++p)
            *reinterpret_cast<uint4*>(&As[b][swzu(p * 32 + xr, xc)]) = rx[s][p];
        #pragma unroll
        for (int p = 0; p < 4; ++p) {
            const int row = p * 16 + wrow;
            ushort4 g4, u4;
            g4.x = f2bf(rg[s][p].x * s_g); g4.y = f2bf(rg[s][p].y * s_g);
            g4.z = f2bf(rg[s][p].z * s_g); g4.w = f2bf(rg[s][p].w * s_g);
            u4.x = f2bf(ru[s][p].x * s_u); u4.y = f2bf(ru[s][p].y * s_u);
            u4.z = f2bf(ru[s][p].z * s_u); u4.w = f2bf(ru[s][p].w * s_u);
            *reinterpret_cast<ushort4*>(&Bg[b][swz8(row, wc4)]) = g4;
            *reinterpret_cast<ushort4*>(&Bu[b][swz8(row, wc4)]) = u4;
        }
    };

    auto COMPUTE = [&](int b) {
        #pragma unroll
        for (int ks = 0; ks < 2; ++ks) {
            const int ku = ks * 4 + (lane >> 4);
            bf16x8_t af[2], gf[2], uf[2];
            #pragma unroll
            for (int i = 0; i < 2; ++i)
                af[i] = *reinterpret_cast<const bf16x8_t*>(
                    &As[b][swzu(wr * 32 + i * 16 + (lane & 15), ku)]);
            #pragma unroll
            for (int j = 0; j < 2; ++j) {
                gf[j] = *reinterpret_cast<const bf16x8_t*>(
                    &Bg[b][swzu(wc * 32 + j * 16 + (lane & 15), ku)]);
                uf[j] = *reinterpret_cast<const bf16x8_t*>(
                    &Bu[b][swzu(wc * 32 + j * 16 + (lane & 15), ku)]);
            }
            #pragma unroll
            for (int i = 0; i < 2; ++i)
                #pragma unroll
                for (int j = 0; j < 2; ++j) {
                    accg[i][j] = MFMA_BF16(af[i], gf[j], accg[i][j]);
                    accu[i][j] = MFMA_BF16(af[i], uf[j], accu[i][j]);
                }
        }
    };

    // Prologue: tiles 0,1 in flight; tile 0 staged to LDS buf0.
    LOADG(0, 0);
    LOADG(1, 1);
    STORE(0, 0, 0);
    WAIT_LGKM0();
    BARRIER();

    for (int kt = 0; kt < NT; kt += 2) {
        if (kt + 2 < NT) LOADG(kt + 2, 0);   // prefetch 2 ahead into freed set 0
        COMPUTE(0);                          // tile kt from buf0
        STORE(kt + 1, 1, 1);                 // counted vmcnt: loads issued 1 iter ago
        WAIT_LGKM0();
        BARRIER();

        if (kt + 3 < NT) LOADG(kt + 3, 1);
        COMPUTE(1);                          // tile kt+1 from buf1
        if (kt + 2 < NT) {
            STORE(kt + 2, 0, 0);
            WAIT_LGKM0();
            BARRIER();
        }
    }

    // epilogue: h = silu(g) * u, bf16
    #pragma unroll
    for (int i = 0; i < 2; ++i)
        #pragma unroll
        for (int j = 0; j < 2; ++j)
            #pragma unroll
            for (int r = 0; r < 4; ++r) {
                const int m = m0 + wr * 32 + i * 16 + (lane >> 4) * 4 + r;
                const int n = n0 + wc * 32 + j * 16 + (lane & 15);
                const float g = accg[i][j][r];
                const float u = accu[i][j][r];
                const float sil = g / (1.0f + __expf(-g));
                hb[(size_t)m * F_DIM + n] = f2bf(sil * u);
            }
}

// ---------------- down GEMM ----------------
// BM=64, BN=128, BK=64. Same 2-deep prefetch + dbuf + raw barriers.
__global__ __launch_bounds__(256, 1) void down_kernel(
    const ushort* __restrict__ hb, const float* __restrict__ wd,
    const float* __restrict__ sd, float* __restrict__ out)
{
    __shared__ ushort As[2][64 * 64];
    __shared__ ushort Bs[2][128 * 64];

    const int tid = threadIdx.x;
    const int lane = tid & 63;
    const int wid = tid >> 6;
    const int wr = wid >> 1, wc = wid & 1;
    const int bn = blockIdx.x, bm = blockIdx.y;
    const int m0 = bm * 64, n0 = bn * 128;

    const int xr = tid >> 3, xc = tid & 7;
    const int wrow = tid >> 4, wc4 = tid & 15;
    const int NT = F_DIM / 64;  // 32 (even)

    uint4 rx[2][2];
    float4 rw[2][8];
    f32x4_t acc[2][4] = {};

    auto LOADG = [&](int kt, int s) {
        const int k0 = kt * 64;
        #pragma unroll
        for (int p = 0; p < 2; ++p)
            rx[s][p] = *reinterpret_cast<const uint4*>(
                &hb[(size_t)(m0 + p * 32 + xr) * F_DIM + k0 + xc * 8]);
        #pragma unroll
        for (int p = 0; p < 8; ++p)
            rw[s][p] = *reinterpret_cast<const float4*>(
                &wd[(size_t)(n0 + p * 16 + wrow) * F_DIM + k0 + wc4 * 4]);
    };

    auto STORE = [&](int kt, int s, int b) {
        const float s_d = sd[bn * (F_DIM / 128) + (kt >> 1)];
        #pragma unroll
        for (int p = 0; p < 2; ++p)
            *reinterpret_cast<uint4*>(&As[b][swzu(p * 32 + xr, xc)]) = rx[s][p];
        #pragma unroll
        for (int p = 0; p < 8; ++p) {
            const int row = p * 16 + wrow;
            ushort4 w4;
            w4.x = f2bf(rw[s][p].x * s_d); w4.y = f2bf(rw[s][p].y * s_d);
            w4.z = f2bf(rw[s][p].z * s_d); w4.w = f2bf(rw[s][p].w * s_d);
            *reinterpret_cast<ushort4*>(&Bs[b][swz8(row, wc4)]) = w4;
        }
    };

    auto COMPUTE = [&](int b) {
        #pragma unroll
        for (int ks = 0; ks < 2; ++ks) {
            const int ku = ks * 4 + (lane >> 4);
            bf16x8_t af[2], bfr[4];
            #pragma unroll
            for (int i = 0; i < 2; ++i)
                af[i] = *reinterpret_cast<const bf16x8_t*>(
                    &As[b][swzu(wr * 32 + i * 16 + (lane & 15), ku)]);
            #pragma unroll
            for (int j = 0; j < 4; ++j)
                bfr[j] = *reinterpret_cast<const bf16x8_t*>(
                    &Bs[b][swzu(wc * 64 + j * 16 + (lane & 15), ku)]);
            #pragma unroll
            for (int i = 0; i < 2; ++i)
                #pragma unroll
                for (int j = 0; j < 4; ++j)
                    acc[i][j] = MFMA_BF16(af[i], bfr[j], acc[i][j]);
        }
    };

    LOADG(0, 0);
    LOADG(1, 1);
    STORE(0, 0, 0);
    WAIT_LGKM0();
    BARRIER();

    for (int kt = 0; kt < NT; kt += 2) {
        if (kt + 2 < NT) LOADG(kt + 2, 0);
        COMPUTE(0);
        STORE(kt + 1, 1, 1);
        WAIT_LGKM0();
        BARRIER();

        if (kt + 3 < NT) LOADG(kt + 3, 1);
        COMPUTE(1);
        if (kt + 2 < NT) {
            STORE(kt + 2, 0, 0);
            WAIT_LGKM0();
            BARRIER();
        }
    }

    #pragma unroll
    for (int i = 0; i < 2; ++i)
        #pragma unroll
        for (int j = 0; j < 4; ++j)
            #pragma unroll
            for (int r = 0; r < 4; ++r) {
                const int m = m0 + wr * 32 + i * 16 + (lane >> 4) * 4 + r;
                const int n = n0 + wc * 64 + j * 16 + (lane & 15);
                out[(size_t)m * H_DIM + n] = acc[i][j][r];
            }
}

extern "C" void kernel_launch(void* const* d_in, const int* in_sizes, int n_in,
                              void* d_out, int out_size, void* d_ws, size_t ws_size,
                              hipStream_t stream) {
    const float* x  = (const float*)d_in[0];
    const float* wg = (const float*)d_in[1];
    const float* sg = (const float*)d_in[2];
    const float* wu = (const float*)d_in[3];
    const float* su = (const float*)d_in[4];
    const float* wd = (const float*)d_in[5];
    const float* sd = (const float*)d_in[6];
    float* out = (float*)d_out;

    ushort* xb = (ushort*)d_ws;                      // 512*7168 bf16 = 7.0 MiB
    ushort* hb = xb + (size_t)T_DIM * H_DIM;         // 512*2048 bf16 = 2.0 MiB

    const int n4 = T_DIM * H_DIM / 4;
    cvt_x_kernel<<<n4 / 256, 256, 0, stream>>>(x, xb, n4);
    gate_up_kernel<<<dim3(F_DIM / 64, T_DIM / 64), 256, 0, stream>>>(xb, wg, sg, wu, su, hb);
    down_kernel<<<dim3(H_DIM / 128, T_DIM / 64), 256, 0, stream>>>(hb, wd, sd, out);
}

// Round 3
// 213.032 us; speedup vs baseline: 1.0514x; 1.0514x over previous
//
#include <hip/hip_runtime.h>
#include <hip/hip_bf16.h>

typedef __bf16 bf16x8_t __attribute__((ext_vector_type(8)));
typedef float f32x4_t __attribute__((ext_vector_type(4)));

#define MFMA_BF16(a, b, c) __builtin_amdgcn_mfma_f32_16x16x32_bf16((a), (b), (c), 0, 0, 0)

static constexpr int T_DIM = 512;
static constexpr int H_DIM = 7168;
static constexpr int F_DIM = 2048;

__device__ __forceinline__ ushort f2bf(float f) {
    return __builtin_bit_cast(ushort, __float2bfloat16(f));
}

// XOR-swizzle for [rows][64-ushort] LDS tiles, 16B-unit granularity.
__device__ __forceinline__ int swzu(int row, int c16) {
    return (row << 6) + (((c16) ^ (row & 7)) << 3);
}
// 8B-granular variant for staging writes (c8 in [0,16))
__device__ __forceinline__ int swz8(int row, int c8) {
    return (row << 6) + ((((c8 >> 1) ^ (row & 7))) << 3) + ((c8 & 1) << 2);
}

__global__ void cvt_x_kernel(const float* __restrict__ in, ushort* __restrict__ outp, int n4) {
    int i = blockIdx.x * 256 + threadIdx.x;
    if (i < n4) {
        float4 v = reinterpret_cast<const float4*>(in)[i];
        ushort4 o;
        o.x = f2bf(v.x); o.y = f2bf(v.y); o.z = f2bf(v.z); o.w = f2bf(v.w);
        reinterpret_cast<ushort4*>(outp)[i] = o;
    }
}

// ---------------- gate+up fused GEMM (split-K) ----------------
// BM=64, BN=64, BK=64. Grid (F/64=32, T/64=8, NSPLIT). blockIdx.z = k-split.
// Single-buffer LDS (24KB), reg prefetch 1 ahead, 4 waves 2x2 (wave 32x32).
// WRITE_H: nsplit==1 path writes silu(g)*u bf16 directly; else fp32 partials.
template <bool WRITE_H>
__global__ __launch_bounds__(256) void gate_up_kernel(
    const ushort* __restrict__ xb, const float* __restrict__ wg,
    const float* __restrict__ sg, const float* __restrict__ wu,
    const float* __restrict__ su, ushort* __restrict__ hb,
    float* __restrict__ gp, float* __restrict__ up_p, int NTS)
{
    __shared__ ushort As[64 * 64];
    __shared__ ushort Bg[64 * 64];
    __shared__ ushort Bu[64 * 64];

    const int tid = threadIdx.x;
    const int lane = tid & 63;
    const int wid = tid >> 6;
    const int wr = wid >> 1, wc = wid & 1;
    const int bn = blockIdx.x, bm = blockIdx.y, bz = blockIdx.z;
    const int m0 = bm * 64, n0 = bn * 64;
    const int ks0 = bz * NTS, ks1 = ks0 + NTS;

    const int xr = tid >> 3, xc = tid & 7;
    const int wrow = tid >> 4, wc4 = tid & 15;

    uint4 rx[2];
    float4 rg[4], ru[4];

    auto LOAD = [&](int kt) {
        const int k0 = kt * 64;
        #pragma unroll
        for (int p = 0; p < 2; ++p)
            rx[p] = *reinterpret_cast<const uint4*>(
                &xb[(size_t)(m0 + p * 32 + xr) * H_DIM + k0 + xc * 8]);
        #pragma unroll
        for (int p = 0; p < 4; ++p) {
            const size_t off = (size_t)(n0 + p * 16 + wrow) * H_DIM + k0 + wc4 * 4;
            rg[p] = *reinterpret_cast<const float4*>(&wg[off]);
            ru[p] = *reinterpret_cast<const float4*>(&wu[off]);
        }
    };

    f32x4_t accg[2][2] = {};
    f32x4_t accu[2][2] = {};

    LOAD(ks0);
    for (int kt = ks0; kt < ks1; ++kt) {
        __syncthreads();
        {   // stage to LDS (dequant + cvt fused for weights)
            const float s_g = sg[(bn >> 1) * (H_DIM / 128) + (kt >> 1)];
            const float s_u = su[(bn >> 1) * (H_DIM / 128) + (kt >> 1)];
            #pragma unroll
            for (int p = 0; p < 2; ++p)
                *reinterpret_cast<uint4*>(&As[swzu(p * 32 + xr, xc)]) = rx[p];
            #pragma unroll
            for (int p = 0; p < 4; ++p) {
                const int row = p * 16 + wrow;
                ushort4 g4, u4;
                g4.x = f2bf(rg[p].x * s_g); g4.y = f2bf(rg[p].y * s_g);
                g4.z = f2bf(rg[p].z * s_g); g4.w = f2bf(rg[p].w * s_g);
                u4.x = f2bf(ru[p].x * s_u); u4.y = f2bf(ru[p].y * s_u);
                u4.z = f2bf(ru[p].z * s_u); u4.w = f2bf(ru[p].w * s_u);
                *reinterpret_cast<ushort4*>(&Bg[swz8(row, wc4)]) = g4;
                *reinterpret_cast<ushort4*>(&Bu[swz8(row, wc4)]) = u4;
            }
        }
        __syncthreads();
        if (kt + 1 < ks1) LOAD(kt + 1);  // prefetch overlaps MFMA below
        #pragma unroll
        for (int ks = 0; ks < 2; ++ks) {
            const int ku = ks * 4 + (lane >> 4);
            bf16x8_t af[2], gf[2], uf[2];
            #pragma unroll
            for (int i = 0; i < 2; ++i)
                af[i] = *reinterpret_cast<const bf16x8_t*>(
                    &As[swzu(wr * 32 + i * 16 + (lane & 15), ku)]);
            #pragma unroll
            for (int j = 0; j < 2; ++j) {
                gf[j] = *reinterpret_cast<const bf16x8_t*>(
                    &Bg[swzu(wc * 32 + j * 16 + (lane & 15), ku)]);
                uf[j] = *reinterpret_cast<const bf16x8_t*>(
                    &Bu[swzu(wc * 32 + j * 16 + (lane & 15), ku)]);
            }
            #pragma unroll
            for (int i = 0; i < 2; ++i)
                #pragma unroll
                for (int j = 0; j < 2; ++j) {
                    accg[i][j] = MFMA_BF16(af[i], gf[j], accg[i][j]);
                    accu[i][j] = MFMA_BF16(af[i], uf[j], accu[i][j]);
                }
        }
    }

    #pragma unroll
    for (int i = 0; i < 2; ++i)
        #pragma unroll
        for (int j = 0; j < 2; ++j)
            #pragma unroll
            for (int r = 0; r < 4; ++r) {
                const int m = m0 + wr * 32 + i * 16 + (lane >> 4) * 4 + r;
                const int n = n0 + wc * 32 + j * 16 + (lane & 15);
                if (WRITE_H) {
                    const float g = accg[i][j][r];
                    const float u = accu[i][j][r];
                    const float sil = g / (1.0f + __expf(-g));
                    hb[(size_t)m * F_DIM + n] = f2bf(sil * u);
                } else {
                    const size_t off = (size_t)bz * T_DIM * F_DIM + (size_t)m * F_DIM + n;
                    gp[off] = accg[i][j][r];
                    up_p[off] = accu[i][j][r];
                }
            }
}

// reduce split-K partials: h = silu(sum g) * (sum u), bf16
__global__ void h_reduce_kernel(const float* __restrict__ gp, const float* __restrict__ up_p,
                                ushort* __restrict__ hb, int nsplit, int n4) {
    int i = blockIdx.x * 256 + threadIdx.x;
    if (i >= n4) return;
    const size_t stride4 = (size_t)T_DIM * F_DIM / 4;
    float4 g = reinterpret_cast<const float4*>(gp)[i];
    float4 u = reinterpret_cast<const float4*>(up_p)[i];
    for (int s = 1; s < nsplit; ++s) {
        float4 g2 = reinterpret_cast<const float4*>(gp)[i + s * stride4];
        float4 u2 = reinterpret_cast<const float4*>(up_p)[i + s * stride4];
        g.x += g2.x; g.y += g2.y; g.z += g2.z; g.w += g2.w;
        u.x += u2.x; u.y += u2.y; u.z += u2.z; u.w += u2.w;
    }
    ushort4 o;
    o.x = f2bf(g.x / (1.0f + __expf(-g.x)) * u.x);
    o.y = f2bf(g.y / (1.0f + __expf(-g.y)) * u.y);
    o.z = f2bf(g.z / (1.0f + __expf(-g.z)) * u.z);
    o.w = f2bf(g.w / (1.0f + __expf(-g.w)) * u.w);
    reinterpret_cast<ushort4*>(hb)[i] = o;
}

// ---------------- down GEMM ----------------
// BM=64, BN=64, BK=64. Grid (H/64=112, T/64=8) = 896 blocks (~3.5/CU).
__global__ __launch_bounds__(256) void down_kernel(
    const ushort* __restrict__ hb, const float* __restrict__ wd,
    const float* __restrict__ sd, float* __restrict__ out)
{
    __shared__ ushort As[64 * 64];
    __shared__ ushort Bs[64 * 64];

    const int tid = threadIdx.x;
    const int lane = tid & 63;
    const int wid = tid >> 6;
    const int wr = wid >> 1, wc = wid & 1;
    const int bn = blockIdx.x, bm = blockIdx.y;
    const int m0 = bm * 64, n0 = bn * 64;

    const int xr = tid >> 3, xc = tid & 7;
    const int wrow = tid >> 4, wc4 = tid & 15;
    const int NT = F_DIM / 64;  // 32

    uint4 rx[2];
    float4 rw[4];

    auto LOAD = [&](int kt) {
        const int k0 = kt * 64;
        #pragma unroll
        for (int p = 0; p < 2; ++p)
            rx[p] = *reinterpret_cast<const uint4*>(
                &hb[(size_t)(m0 + p * 32 + xr) * F_DIM + k0 + xc * 8]);
        #pragma unroll
        for (int p = 0; p < 4; ++p)
            rw[p] = *reinterpret_cast<const float4*>(
                &wd[(size_t)(n0 + p * 16 + wrow) * F_DIM + k0 + wc4 * 4]);
    };

    f32x4_t acc[2][2] = {};

    LOAD(0);
    for (int kt = 0; kt < NT; ++kt) {
        __syncthreads();
        {
            const float s_d = sd[(bn >> 1) * (F_DIM / 128) + (kt >> 1)];
            #pragma unroll
            for (int p = 0; p < 2; ++p)
                *reinterpret_cast<uint4*>(&As[swzu(p * 32 + xr, xc)]) = rx[p];
            #pragma unroll
            for (int p = 0; p < 4; ++p) {
                const int row = p * 16 + wrow;
                ushort4 w4;
                w4.x = f2bf(rw[p].x * s_d); w4.y = f2bf(rw[p].y * s_d);
                w4.z = f2bf(rw[p].z * s_d); w4.w = f2bf(rw[p].w * s_d);
                *reinterpret_cast<ushort4*>(&Bs[swz8(row, wc4)]) = w4;
            }
        }
        __syncthreads();
        if (kt + 1 < NT) LOAD(kt + 1);
        #pragma unroll
        for (int ks = 0; ks < 2; ++ks) {
            const int ku = ks * 4 + (lane >> 4);
            bf16x8_t af[2], bfr[2];
            #pragma unroll
            for (int i = 0; i < 2; ++i)
                af[i] = *reinterpret_cast<const bf16x8_t*>(
                    &As[swzu(wr * 32 + i * 16 + (lane & 15), ku)]);
            #pragma unroll
            for (int j = 0; j < 2; ++j)
                bfr[j] = *reinterpret_cast<const bf16x8_t*>(
                    &Bs[swzu(wc * 32 + j * 16 + (lane & 15), ku)]);
            #pragma unroll
            for (int i = 0; i < 2; ++i)
                #pragma unroll
                for (int j = 0; j < 2; ++j)
                    acc[i][j] = MFMA_BF16(af[i], bfr[j], acc[i][j]);
        }
    }

    #pragma unroll
    for (int i = 0; i < 2; ++i)
        #pragma unroll
        for (int j = 0; j < 2; ++j)
            #pragma unroll
            for (int r = 0; r < 4; ++r) {
                const int m = m0 + wr * 32 + i * 16 + (lane >> 4) * 4 + r;
                const int n = n0 + wc * 32 + j * 16 + (lane & 15);
                out[(size_t)m * H_DIM + n] = acc[i][j][r];
            }
}

extern "C" void kernel_launch(void* const* d_in, const int* in_sizes, int n_in,
                              void* d_out, int out_size, void* d_ws, size_t ws_size,
                              hipStream_t stream) {
    const float* x  = (const float*)d_in[0];
    const float* wg = (const float*)d_in[1];
    const float* sg = (const float*)d_in[2];
    const float* wu = (const float*)d_in[3];
    const float* su = (const float*)d_in[4];
    const float* wd = (const float*)d_in[5];
    const float* sd = (const float*)d_in[6];
    float* out = (float*)d_out;

    ushort* xb = (ushort*)d_ws;                       // 7.34 MB
    ushort* hb = xb + (size_t)T_DIM * H_DIM;          // 2.10 MB
    float*  gp = (float*)(hb + (size_t)T_DIM * F_DIM);

    const size_t base_b = (size_t)T_DIM * H_DIM * 2 + (size_t)T_DIM * F_DIM * 2;
    const size_t split_b = (size_t)T_DIM * F_DIM * 4 * 2;  // g+u fp32 per split

    int nsplit = 1;
    if (ws_size >= base_b + 4 * split_b) nsplit = 4;
    else if (ws_size >= base_b + 2 * split_b) nsplit = 2;
    float* up_p = gp + (size_t)nsplit * T_DIM * F_DIM;

    const int n4x = T_DIM * H_DIM / 4;
    cvt_x_kernel<<<n4x / 256, 256, 0, stream>>>(x, xb, n4x);

    if (nsplit == 1) {
        gate_up_kernel<true><<<dim3(F_DIM / 64, T_DIM / 64, 1), 256, 0, stream>>>(
            xb, wg, sg, wu, su, hb, gp, up_p, H_DIM / 64);
    } else {
        gate_up_kernel<false><<<dim3(F_DIM / 64, T_DIM / 64, nsplit), 256, 0, stream>>>(
            xb, wg, sg, wu, su, hb, gp, up_p, H_DIM / 64 / nsplit);
        const int n4h = T_DIM * F_DIM / 4;
        h_reduce_kernel<<<n4h / 256, 256, 0, stream>>>(gp, up_p, hb, nsplit, n4h);
    }

    down_kernel<<<dim3(H_DIM / 64, T_DIM / 64), 256, 0, stream>>>(hb, wd, sd, out);
}

// Round 4
// 143.585 us; speedup vs baseline: 1.5599x; 1.4837x over previous
//
#include <hip/hip_runtime.h>
#include <hip/hip_bf16.h>

typedef __bf16 bf16x8_t __attribute__((ext_vector_type(8)));
typedef float f32x4_t __attribute__((ext_vector_type(4)));

#define MFMA_BF16(a, b, c) __builtin_amdgcn_mfma_f32_16x16x32_bf16((a), (b), (c), 0, 0, 0)

static constexpr int T_DIM = 512;
static constexpr int H_DIM = 7168;
static constexpr int F_DIM = 2048;

__device__ __forceinline__ ushort f2bf(float f) {
    return __builtin_bit_cast(ushort, __float2bfloat16(f));
}

// XOR-swizzle for [rows][64-ushort] LDS tiles, 16B-unit granularity.
__device__ __forceinline__ int swzu(int row, int c16) {
    return (row << 6) + (((c16) ^ (row & 7)) << 3);
}
// 8B-granular variant for staging writes (c8 in [0,16))
__device__ __forceinline__ int swz8(int row, int c8) {
    return (row << 6) + ((((c8 >> 1) ^ (row & 7))) << 3) + ((c8 & 1) << 2);
}

__global__ void cvt_x_kernel(const float* __restrict__ in, ushort* __restrict__ outp, int n4) {
    int i = blockIdx.x * 256 + threadIdx.x;
    if (i < n4) {
        float4 v = reinterpret_cast<const float4*>(in)[i];
        ushort4 o;
        o.x = f2bf(v.x); o.y = f2bf(v.y); o.z = f2bf(v.z); o.w = f2bf(v.w);
        reinterpret_cast<ushort4*>(outp)[i] = o;
    }
}

// ---------------- gate+up fused GEMM, combined N=4096, split-K ----------------
// BM=128, BN=128, BK=64. 512 thr = 8 waves (2m x 4n), wave tile 64x32.
// Double-buffered LDS, 1 barrier/k-tile: LOADG(t+1) / COMPUTE(b) / STORE(b^1).
// Grid (32, 4, nsplit): id%8 == bn%8 -> weight-sharing blocks share an XCD L2.
__global__ __launch_bounds__(512, 4) void gate_up_kernel(
    const ushort* __restrict__ xb, const float* __restrict__ wg,
    const float* __restrict__ sg, const float* __restrict__ wu,
    const float* __restrict__ su, float* __restrict__ gp, int NTS)
{
    __shared__ ushort As[2][128 * 64];
    __shared__ ushort Bs[2][128 * 64];

    const int tid = threadIdx.x;
    const int lane = tid & 63;
    const int wid = tid >> 6;
    const int wr = wid >> 2, wcn = wid & 3;   // wave 64x32 tile at (wr*64, wcn*32)
    const int bn = blockIdx.x, bm = blockIdx.y, bz = blockIdx.z;
    const int m0 = bm * 128;
    const int ks0 = bz * NTS, ks1 = ks0 + NTS;

    // combined-N weight base + scale row (BN=128 == scale block size)
    const float* __restrict__ Wb = (bn < 16) ? wg : wu;
    const float* __restrict__ srow = ((bn < 16) ? sg : su) + (size_t)(bn & 15) * (H_DIM / 128);
    const int nb = (bn & 15) * 128;

    // A staging: 2 x uint4/thread; slot q*512+tid -> row q*64+(tid>>3), u=tid&7
    const int ar = tid >> 3, au = tid & 7;
    // B staging: 4 x float4/thread; row (tid>>4)+p*32, f4 col tid&15
    const int br = tid >> 4, bf4 = tid & 15;

    uint4 ra[2];
    float4 rb[4];
    f32x4_t acc[4][2] = {};

    auto LOADG = [&](int kt) {
        const int k0 = kt * 64;
        #pragma unroll
        for (int q = 0; q < 2; ++q)
            ra[q] = *reinterpret_cast<const uint4*>(
                &xb[(size_t)(m0 + q * 64 + ar) * H_DIM + k0 + au * 8]);
        #pragma unroll
        for (int p = 0; p < 4; ++p)
            rb[p] = *reinterpret_cast<const float4*>(
                &Wb[(size_t)(nb + p * 32 + br) * H_DIM + k0 + bf4 * 4]);
    };

    auto STORE = [&](int kt, int b) {
        const float s = srow[kt >> 1];
        #pragma unroll
        for (int q = 0; q < 2; ++q)
            *reinterpret_cast<uint4*>(&As[b][swzu(q * 64 + ar, au)]) = ra[q];
        #pragma unroll
        for (int p = 0; p < 4; ++p) {
            const int row = p * 32 + br;
            ushort4 w4;
            w4.x = f2bf(rb[p].x * s); w4.y = f2bf(rb[p].y * s);
            w4.z = f2bf(rb[p].z * s); w4.w = f2bf(rb[p].w * s);
            *reinterpret_cast<ushort4*>(&Bs[b][swz8(row, bf4)]) = w4;
        }
    };

    auto COMPUTE = [&](int b) {
        #pragma unroll
        for (int ks = 0; ks < 2; ++ks) {
            const int ku = ks * 4 + (lane >> 4);
            bf16x8_t af[4], bf[2];
            #pragma unroll
            for (int i = 0; i < 4; ++i)
                af[i] = *reinterpret_cast<const bf16x8_t*>(
                    &As[b][swzu(wr * 64 + i * 16 + (lane & 15), ku)]);
            #pragma unroll
            for (int j = 0; j < 2; ++j)
                bf[j] = *reinterpret_cast<const bf16x8_t*>(
                    &Bs[b][swzu(wcn * 32 + j * 16 + (lane & 15), ku)]);
            #pragma unroll
            for (int i = 0; i < 4; ++i)
                #pragma unroll
                for (int j = 0; j < 2; ++j)
                    acc[i][j] = MFMA_BF16(af[i], bf[j], acc[i][j]);
        }
    };

    LOADG(ks0);
    STORE(ks0, 0);
    __syncthreads();

    int b = 0;
    for (int kt = ks0; kt < ks1; ++kt) {
        if (kt + 1 < ks1) LOADG(kt + 1);
        COMPUTE(b);
        if (kt + 1 < ks1) STORE(kt + 1, b ^ 1);
        __syncthreads();
        b ^= 1;
    }

    // fp32 partials: P[bz][T][4096]
    #pragma unroll
    for (int i = 0; i < 4; ++i)
        #pragma unroll
        for (int j = 0; j < 2; ++j)
            #pragma unroll
            for (int r = 0; r < 4; ++r) {
                const int m = m0 + wr * 64 + i * 16 + (lane >> 4) * 4 + r;
                const int nc = bn * 128 + wcn * 32 + j * 16 + (lane & 15);
                gp[(size_t)bz * T_DIM * 4096 + (size_t)m * 4096 + nc] = acc[i][j][r];
            }
}

// reduce split-K partials: h = silu(sum g) * (sum u), bf16. P cols [0,2048)=g, [2048,4096)=u
__global__ void h_reduce_kernel(const float* __restrict__ gp, ushort* __restrict__ hb,
                                int nsplit, int n4) {
    int i = blockIdx.x * 256 + threadIdx.x;
    if (i >= n4) return;
    const int m = i >> 9;             // 512 float4 per 2048-col row
    const int c4 = i & 511;
    const size_t base = (size_t)m * 4096 + c4 * 4;
    const size_t stride = (size_t)T_DIM * 4096;
    float4 g = *reinterpret_cast<const float4*>(&gp[base]);
    float4 u = *reinterpret_cast<const float4*>(&gp[base + 2048]);
    for (int s = 1; s < nsplit; ++s) {
        float4 g2 = *reinterpret_cast<const float4*>(&gp[s * stride + base]);
        float4 u2 = *reinterpret_cast<const float4*>(&gp[s * stride + base + 2048]);
        g.x += g2.x; g.y += g2.y; g.z += g2.z; g.w += g2.w;
        u.x += u2.x; u.y += u2.y; u.z += u2.z; u.w += u2.w;
    }
    ushort4 o;
    o.x = f2bf(g.x / (1.0f + __expf(-g.x)) * u.x);
    o.y = f2bf(g.y / (1.0f + __expf(-g.y)) * u.y);
    o.z = f2bf(g.z / (1.0f + __expf(-g.z)) * u.z);
    o.w = f2bf(g.w / (1.0f + __expf(-g.w)) * u.w);
    reinterpret_cast<ushort4*>(hb)[i] = o;
}

// ---------------- down GEMM ----------------
// BM=128, BN=128, BK=64, K=2048. Grid (56, 4) -> id%8 == bn%8 (56%8==0).
__global__ __launch_bounds__(512, 4) void down_kernel(
    const ushort* __restrict__ hb, const float* __restrict__ wd,
    const float* __restrict__ sd, float* __restrict__ out)
{
    __shared__ ushort As[2][128 * 64];
    __shared__ ushort Bs[2][128 * 64];

    const int tid = threadIdx.x;
    const int lane = tid & 63;
    const int wid = tid >> 6;
    const int wr = wid >> 2, wcn = wid & 3;
    const int bn = blockIdx.x, bm = blockIdx.y;
    const int m0 = bm * 128;
    const float* __restrict__ srow = sd + (size_t)bn * (F_DIM / 128);
    const int nb = bn * 128;
    const int NT = F_DIM / 64;  // 32

    const int ar = tid >> 3, au = tid & 7;
    const int br = tid >> 4, bf4 = tid & 15;

    uint4 ra[2];
    float4 rb[4];
    f32x4_t acc[4][2] = {};

    auto LOADG = [&](int kt) {
        const int k0 = kt * 64;
        #pragma unroll
        for (int q = 0; q < 2; ++q)
            ra[q] = *reinterpret_cast<const uint4*>(
                &hb[(size_t)(m0 + q * 64 + ar) * F_DIM + k0 + au * 8]);
        #pragma unroll
        for (int p = 0; p < 4; ++p)
            rb[p] = *reinterpret_cast<const float4*>(
                &wd[(size_t)(nb + p * 32 + br) * F_DIM + k0 + bf4 * 4]);
    };

    auto STORE = [&](int kt, int b) {
        const float s = srow[kt >> 1];
        #pragma unroll
        for (int q = 0; q < 2; ++q)
            *reinterpret_cast<uint4*>(&As[b][swzu(q * 64 + ar, au)]) = ra[q];
        #pragma unroll
        for (int p = 0; p < 4; ++p) {
            const int row = p * 32 + br;
            ushort4 w4;
            w4.x = f2bf(rb[p].x * s); w4.y = f2bf(rb[p].y * s);
            w4.z = f2bf(rb[p].z * s); w4.w = f2bf(rb[p].w * s);
            *reinterpret_cast<ushort4*>(&Bs[b][swz8(row, bf4)]) = w4;
        }
    };

    auto COMPUTE = [&](int b) {
        #pragma unroll
        for (int ks = 0; ks < 2; ++ks) {
            const int ku = ks * 4 + (lane >> 4);
            bf16x8_t af[4], bf[2];
            #pragma unroll
            for (int i = 0; i < 4; ++i)
                af[i] = *reinterpret_cast<const bf16x8_t*>(
                    &As[b][swzu(wr * 64 + i * 16 + (lane & 15), ku)]);
            #pragma unroll
            for (int j = 0; j < 2; ++j)
                bf[j] = *reinterpret_cast<const bf16x8_t*>(
                    &Bs[b][swzu(wcn * 32 + j * 16 + (lane & 15), ku)]);
            #pragma unroll
            for (int i = 0; i < 4; ++i)
                #pragma unroll
                for (int j = 0; j < 2; ++j)
                    acc[i][j] = MFMA_BF16(af[i], bf[j], acc[i][j]);
        }
    };

    LOADG(0);
    STORE(0, 0);
    __syncthreads();

    int b = 0;
    for (int kt = 0; kt < NT; ++kt) {
        if (kt + 1 < NT) LOADG(kt + 1);
        COMPUTE(b);
        if (kt + 1 < NT) STORE(kt + 1, b ^ 1);
        __syncthreads();
        b ^= 1;
    }

    #pragma unroll
    for (int i = 0; i < 4; ++i)
        #pragma unroll
        for (int j = 0; j < 2; ++j)
            #pragma unroll
            for (int r = 0; r < 4; ++r) {
                const int m = m0 + wr * 64 + i * 16 + (lane >> 4) * 4 + r;
                const int nc = nb + wcn * 32 + j * 16 + (lane & 15);
                out[(size_t)m * H_DIM + nc] = acc[i][j][r];
            }
}

extern "C" void kernel_launch(void* const* d_in, const int* in_sizes, int n_in,
                              void* d_out, int out_size, void* d_ws, size_t ws_size,
                              hipStream_t stream) {
    const float* x  = (const float*)d_in[0];
    const float* wg = (const float*)d_in[1];
    const float* sg = (const float*)d_in[2];
    const float* wu = (const float*)d_in[3];
    const float* su = (const float*)d_in[4];
    const float* wd = (const float*)d_in[5];
    const float* sd = (const float*)d_in[6];
    float* out = (float*)d_out;

    ushort* xb = (ushort*)d_ws;                       // 7.34 MB
    ushort* hb = xb + (size_t)T_DIM * H_DIM;          // 2.10 MB
    float*  gp = (float*)(hb + (size_t)T_DIM * F_DIM);

    const size_t base_b = (size_t)T_DIM * H_DIM * 2 + (size_t)T_DIM * F_DIM * 2;
    const size_t split_b = (size_t)T_DIM * 4096 * 4;  // combined g|u fp32 per split

    int nsplit = 1;
    if (ws_size >= base_b + 4 * split_b) nsplit = 4;
    else if (ws_size >= base_b + 2 * split_b) nsplit = 2;

    const int n4x = T_DIM * H_DIM / 4;
    cvt_x_kernel<<<n4x / 256, 256, 0, stream>>>(x, xb, n4x);

    gate_up_kernel<<<dim3(32, T_DIM / 128, nsplit), 512, 0, stream>>>(
        xb, wg, sg, wu, su, gp, (H_DIM / 64) / nsplit);

    const int n4h = T_DIM * F_DIM / 4;
    h_reduce_kernel<<<n4h / 256, 256, 0, stream>>>(gp, hb, nsplit, n4h);

    down_kernel<<<dim3(H_DIM / 128, T_DIM / 128), 512, 0, stream>>>(hb, wd, sd, out);
}